// Round 20
// baseline (108.871 us; speedup 1.0000x reference)
//
#include <hip/hip_runtime.h>
#include <hip/hip_bf16.h>
#include <math.h>

// Problem constants (B=2, L=2048, d_model=512, H=8, D=64, MAX_POS=2048)
#define B_ 2
#define L_ 2048
#define H_ 8
#define D_ 64
#define DM_ 512

typedef unsigned short u16;
typedef __attribute__((ext_vector_type(8))) short bf16x8;
typedef __attribute__((ext_vector_type(4))) float f32x4;

static const size_t NQ = (size_t)B_ * H_ * L_ * D_;   // 2,097,152 elems per (B,H,L,D) tensor

// Native fp32->bf16 (RNE) via the compiler's bfloat cast — lowers to the HW
// convert on gfx950 (m240: scalar cast beats hand-written cvt_pk asm).
__device__ __forceinline__ u16 f2bf(float x) {
  __hip_bfloat16 h = __float2bfloat16(x);
  return *reinterpret_cast<u16*>(&h);
}
__device__ __forceinline__ float bf2f(u16 x) {
  union { unsigned u; float f; } v; v.u = ((unsigned)x) << 16; return v.f;
}

// ---------------------------------------------------------------------------
// Fused preprocessing (all independent; one launch):
//   blocks [0,2048)    : cast hs fp32 -> bf16
//   blocks [2048,2304) : transpose+cast W[4] -> wt bf16 [mat][n][k]
//   blocks [2304,2336) : stable rank (brute-force count of smaller keys)
//   blocks [2336,2592) : RoPE cos/sin table [2048][32]
//   block  2592        : transpose+cast Wru -> wrut bf16 [256][64]
// ---------------------------------------------------------------------------
__global__ __launch_bounds__(256) void prep_kernel(
    const float* __restrict__ hs,
    const float* __restrict__ Wq, const float* __restrict__ Wk,
    const float* __restrict__ Wv, const float* __restrict__ Wo,
    const float* __restrict__ Wru,
    const int* __restrict__ pos_row, const int* __restrict__ pos_col,
    u16* __restrict__ hsb, u16* __restrict__ wt, u16* __restrict__ wrut,
    float* __restrict__ cost, float* __restrict__ sint,
    int* __restrict__ sidx, int* __restrict__ rank) {
  __shared__ unsigned smbuf[2080];    // 8320 B: castWt tile (64x65 u16) / rank keys (2048 u32)
  const int blk = blockIdx.x;
  const int tid = threadIdx.x;

  if (blk < 2048) {                   // ---- cast_hs ----
    int g = blk * 256 + tid;
    float4 x = *(const float4*)&hs[(size_t)g * 4];
    ushort4 o;
    o.x = f2bf(x.x); o.y = f2bf(x.y); o.z = f2bf(x.z); o.w = f2bf(x.w);
    *(ushort4*)&hsb[(size_t)g * 4] = o;
  } else if (blk < 2304) {            // ---- castWt ----
    int idx = blk - 2048;             // 0..255
    u16 (*tile)[65] = (u16(*)[65])smbuf;
    const int mmat = idx >> 6;
    const float* W = (mmat == 0) ? Wq : (mmat == 1) ? Wk : (mmat == 2) ? Wv : Wo;
    const int n0 = (idx & 7) * 64, k0 = ((idx >> 3) & 7) * 64;
    {
      int r = tid >> 2, cq = tid & 3;
      const float* src = W + (size_t)(k0 + r) * 512 + n0 + cq * 16;
      #pragma unroll
      for (int j4 = 0; j4 < 4; ++j4) {
        float4 x = *(const float4*)&src[j4 * 4];
        int c = cq * 16 + j4 * 4;
        tile[r][c + 0] = f2bf(x.x); tile[r][c + 1] = f2bf(x.y);
        tile[r][c + 2] = f2bf(x.z); tile[r][c + 3] = f2bf(x.w);
      }
    }
    __syncthreads();
    {
      int n = tid >> 2, rq = tid & 3;
      u16 arr[16];
      #pragma unroll
      for (int i = 0; i < 16; ++i) arr[i] = tile[rq * 16 + i][n];
      u16* dst = wt + ((size_t)mmat * 512 + n0 + n) * 512 + k0 + rq * 16;
      *(uint4*)(dst)     = *(uint4*)&arr[0];
      *(uint4*)(dst + 8) = *(uint4*)&arr[8];
    }
  } else if (blk < 2336) {            // ---- rank ----
    unsigned* keys = smbuf;
    const int bx = blk - 2304;        // 0..31
    const int bo = bx >> 3, chunk = bx & 7;
    const int b = bo >> 1, o = bo & 1;
    const int* pos = (o ? pos_col : pos_row) + b * L_;
    for (int i = tid; i < L_; i += 256)
      keys[i] = (((unsigned)pos[i]) << 11) | (unsigned)i;
    __syncthreads();
    const int i = chunk * 256 + tid;
    const unsigned ki = keys[i];
    int cnt = 0;
    #pragma unroll 4
    for (int j = 0; j < L_; j += 4) {
      uint4 kj = *(const uint4*)&keys[j];
      cnt += (kj.x < ki) + (kj.y < ki) + (kj.z < ki) + (kj.w < ki);
    }
    sidx[bo * L_ + cnt] = i;
    rank[bo * L_ + i] = cnt;
  } else if (blk < 2592) {            // ---- rope_table ----
    int g = (blk - 2336) * 256 + tid; // 0..65535
    int f = g & 31, p = g >> 5;
    double th = pow(10000.0, -(double)(2 * f) / 64.0);
    float ang = (float)p * (float)th;
    cost[g] = cosf(ang);
    sint[g] = sinf(ang);
  } else {                            // ---- cast_wrut ----
    const int n = tid;
    #pragma unroll
    for (int k = 0; k < 64; ++k)
      wrut[n * 64 + k] = f2bf(Wru[k * 256 + n]);
  }
}

// ---------------------------------------------------------------------------
// bf16 MFMA GEMM: C(Mx512) = A(Mx512 bf16) @ Wt^T + bias, Wt is [n][k] bf16.
// Tile BM=128, BN=64, BK=64; 256 threads (4 waves).
// MODE 0: out-projection with FUSED COMBINE: the A tile is built on the fly
//   as w0*os_row[bh][rank_row[l]][d] + w1*os_col[bh][rank_col[l]][d]
//   (bit-identical arithmetic to the old combine kernel; each element
//   combined exactly once since each kb covers distinct columns).
//   fp32 row-major out, bias b0, mat 3.
// MODE 1: fused QKV -> bf16 outputs Ob0/Ob1/Ob2 in (B,H,L,D) layout.
// ---------------------------------------------------------------------------
template <int MODE>
__global__ __launch_bounds__(256) void gemm_bf16_kernel(
    const u16* __restrict__ A, const u16* __restrict__ wt,
    const u16* __restrict__ osb, const int* __restrict__ rank,
    const float* __restrict__ rw,
    const float* __restrict__ b0, const float* __restrict__ b1, const float* __restrict__ b2,
    float* __restrict__ Of,
    u16* __restrict__ Ob0, u16* __restrict__ Ob1, u16* __restrict__ Ob2) {
  const int m0 = blockIdx.x * 128;
  int by = blockIdx.y;
  int which = 0;
  if (MODE == 1) { which = by >> 3; by &= 7; }
  const int n0 = by * 64;
  const float* bias = (MODE == 0) ? b0 : (which == 0) ? b0 : (which == 1) ? b1 : b2;
  u16* Ob = (MODE == 0) ? nullptr : (which == 0) ? Ob0 : (which == 1) ? Ob1 : Ob2;
  const u16* Wt = wt + (size_t)((MODE == 0) ? 3 : which) * 512 * 512;

  __shared__ u16 As[128 * 64];
  __shared__ u16 Bs[64 * 64];

  const int tid = threadIdx.x;
  const int w  = tid >> 6;
  const int l  = tid & 63;
  const int lg = l >> 4;
  const int ll = l & 15;

  f32x4 acc[2][4];
  #pragma unroll
  for (int i = 0; i < 2; ++i)
    #pragma unroll
    for (int j = 0; j < 4; ++j) acc[i][j] = (f32x4){0.f, 0.f, 0.f, 0.f};

  for (int kb = 0; kb < 512; kb += 64) {
    #pragma unroll
    for (int i = 0; i < 4; ++i) {           // A tile: 1024 granules
      int gi = i * 256 + tid;
      int r = gi >> 3, g = gi & 7;
      if (MODE == 1) {
        bf16x8 x = *(const bf16x8*)&A[(size_t)(m0 + r) * 512 + kb + g * 8];
        *(bf16x8*)&As[r * 64 + ((g ^ (r & 7)) << 3)] = x;
      } else {
        // fused combine: ctx[row][kb+g*8 .. +7]
        int row = m0 + r;
        int b = row >> 11, ls = row & 2047;
        int bh = b * 8 + (kb >> 6);         // kb spans exactly one head
        int rr = rank[(b * 2 + 0) * L_ + ls];
        int rc = rank[(b * 2 + 1) * L_ + ls];
        float w0 = rw[(((size_t)bh) * L_ + ls) * 2 + 0];
        float w1 = rw[(((size_t)bh) * L_ + ls) * 2 + 1];
        bf16x8 xr = *(const bf16x8*)&osb[(((size_t)bh) * L_ + rr) * 64 + g * 8];
        bf16x8 xc = *(const bf16x8*)&osb[(((size_t)(16 + bh)) * L_ + rc) * 64 + g * 8];
        u16 ov[8];
        #pragma unroll
        for (int j = 0; j < 8; ++j)
          ov[j] = f2bf(w0 * bf2f((u16)xr[j]) + w1 * bf2f((u16)xc[j]));
        *(bf16x8*)&As[r * 64 + ((g ^ (r & 7)) << 3)] = *(const bf16x8*)ov;
      }
    }
    #pragma unroll
    for (int i = 0; i < 2; ++i) {           // B tile: 512 granules
      int gi = i * 256 + tid;
      int n = gi >> 3, g = gi & 7;
      bf16x8 x = *(const bf16x8*)&Wt[(size_t)(n0 + n) * 512 + kb + g * 8];
      *(bf16x8*)&Bs[n * 64 + ((g ^ (n & 7)) << 3)] = x;
    }
    __syncthreads();
    #pragma unroll
    for (int kc = 0; kc < 2; ++kc) {
      bf16x8 ar[2], br[4];
      #pragma unroll
      for (int mr = 0; mr < 2; ++mr) {
        int row = w * 32 + mr * 16 + ll;
        ar[mr] = *(const bf16x8*)&As[row * 64 + (((kc * 4 + lg) ^ (row & 7)) << 3)];
      }
      #pragma unroll
      for (int nt = 0; nt < 4; ++nt) {
        int n = nt * 16 + ll;
        br[nt] = *(const bf16x8*)&Bs[n * 64 + (((kc * 4 + lg) ^ (n & 7)) << 3)];
      }
      #pragma unroll
      for (int mr = 0; mr < 2; ++mr)
        #pragma unroll
        for (int nt = 0; nt < 4; ++nt)
          acc[mr][nt] = __builtin_amdgcn_mfma_f32_16x16x32_bf16(ar[mr], br[nt], acc[mr][nt], 0, 0, 0);
    }
    __syncthreads();
  }

  #pragma unroll
  for (int mr = 0; mr < 2; ++mr) {
    #pragma unroll
    for (int nt = 0; nt < 4; ++nt) {
      int col = n0 + nt * 16 + ll;
      float bv = bias[col];
      #pragma unroll
      for (int r = 0; r < 4; ++r) {
        int row = m0 + w * 32 + mr * 16 + lg * 4 + r;
        float val = acc[mr][nt][r] + bv;
        if (MODE == 0) {
          Of[(size_t)row * 512 + col] = val;
        } else {
          int b = row >> 11, ls = row & 2047;
          int h = col >> 6, d = col & 63;
          size_t idx = (((size_t)(b * 8 + h)) * L_ + ls) * D_ + d;
          Ob[idx] = f2bf(val);
        }
      }
    }
  }
}

// ---------------------------------------------------------------------------
// Fused gather (bf16 inputs from the QKV GEMM):
//   blocks [0,8192)    : RoPE + gather q,k -> sorted bf16.
//     Q pre-scale folds log2(e): 0.125*log2(e) — attention computes softmax
//     in the exp2 domain (p = exp2(s) = exp(s_orig/8), one v_exp per score).
//   blocks [8192,9216) : gather + transpose V -> vt [o][bh][d][key]
// ---------------------------------------------------------------------------
#define QSCALE 0.18033688011f   // 0.125 * log2(e)

__global__ __launch_bounds__(256) void gather_kernel(
    const u16* __restrict__ qb, const u16* __restrict__ kb, const u16* __restrict__ vb,
    const int* __restrict__ pos_row, const int* __restrict__ pos_col,
    const int* __restrict__ sidx,
    const float* __restrict__ cost, const float* __restrict__ sint,
    u16* __restrict__ qs, u16* __restrict__ ks, u16* __restrict__ vt) {
  __shared__ u16 tile[64][72];        // stride 72 u16 = 144 B (16B-aligned rows)
  const int blk = blockIdx.x;
  const int tid = threadIdx.x;

  if (blk < 8192) {                   // ---- rope_gather ----
    int g = blk * 256 + tid;          // 2,097,152 total
    int i5 = g & 31;
    int r  = (g >> 5) & 2047;
    int h  = (g >> 16) & 7;
    int b  = (g >> 19) & 1;
    int o  = (g >> 20) & 1;

    int bo = b * 2 + o;
    int lsrc = sidx[bo * L_ + r];
    const int* pos = o ? pos_col : pos_row;
    int p = pos[b * L_ + lsrc];

    size_t srcoff = (((size_t)(b * 8 + h)) * L_ + lsrc) * D_ + i5 * 2;
    unsigned qu = *(const unsigned*)&qb[srcoff];
    unsigned ku = *(const unsigned*)&kb[srcoff];
    float q2x = bf2f((u16)qu), q2y = bf2f((u16)(qu >> 16));
    float k2x = bf2f((u16)ku), k2y = bf2f((u16)(ku >> 16));

    int f0 = (2 * i5) & 31;
    int f1 = (2 * i5 + 1) & 31;
    float c0 = cost[p * 32 + f0], c1 = cost[p * 32 + f1];
    float s0 = sint[p * 32 + f0], s1 = sint[p * 32 + f1];

    float qx = (q2x * c0 - q2y * s0) * QSCALE;
    float qy = (q2y * c1 + q2x * s1) * QSCALE;
    float kx = k2x * c0 - k2y * s0;
    float ky = k2y * c1 + k2x * s1;

    size_t dst = (((size_t)(o * 16 + b * 8 + h)) * L_ + r) * D_ + i5 * 2;
    qs[dst] = f2bf(qx); qs[dst + 1] = f2bf(qy);
    ks[dst] = f2bf(kx); ks[dst + 1] = f2bf(ky);
  } else {                            // ---- vt (pure gather+transpose copy) ----
    int idx = blk - 8192;             // 0..1023
    const int rt = idx & 31, bh = (idx >> 5) & 15, o = idx >> 9;
    const int b = bh >> 3;
    {
      int r = tid >> 2, dq = tid & 3;
      int lsrc = sidx[(b * 2 + o) * L_ + rt * 64 + r];
      const u16* src = vb + ((size_t)bh * L_ + lsrc) * D_ + dq * 16;
      *(uint4*)&tile[r][dq * 16]     = *(const uint4*)&src[0];
      *(uint4*)&tile[r][dq * 16 + 8] = *(const uint4*)&src[8];
    }
    __syncthreads();
    {
      int d = tid >> 2, rq = tid & 3;
      u16 arr[16];
      #pragma unroll
      for (int i = 0; i < 16; ++i) arr[i] = tile[rq * 16 + i][d];
      u16* dst = vt + (((size_t)(o * 16 + bh)) * D_ + d) * L_ + rt * 64 + rq * 16;
      *(uint4*)(dst)     = *(uint4*)&arr[0];
      *(uint4*)(dst + 8) = *(uint4*)&arr[8];
    }
  }
}

// ---------------------------------------------------------------------------
// Merged attention + router launch (1024 blocks x 512 threads):
//   blocks [0,512)    : causal flash attention
//   blocks [512,1024) : fused MFMA router (independent — fills attn drain)
// ---------------------------------------------------------------------------
template <bool MASK>
__device__ __forceinline__ void attn_tile(
    const u16* __restrict__ Kbuf,    // rows=keys(64), stride 64, swizzled
    const u16* __restrict__ Vbuf,    // rows=d(64), stride 64 (one key-half)
    u16* __restrict__ pw,
    const bf16x8 qf[2], f32x4 accO[4], float psum[4],
    int lg, int ll, int wsub) {
  f32x4 sA[4];
  __builtin_amdgcn_s_setprio(1);
  #pragma unroll
  for (int nt = 0; nt < 4; ++nt) {
    int kr = nt * 16 + ll;
    bf16x8 k0 = *(const bf16x8*)&Kbuf[kr * 64 + ((lg ^ (kr & 7)) << 3)];
    bf16x8 k1 = *(const bf16x8*)&Kbuf[kr * 64 + (((4 + lg) ^ (kr & 7)) << 3)];
    f32x4 z = (f32x4){0.f, 0.f, 0.f, 0.f};
    z = __builtin_amdgcn_mfma_f32_16x16x32_bf16(qf[0], k0, z, 0, 0, 0);
    z = __builtin_amdgcn_mfma_f32_16x16x32_bf16(qf[1], k1, z, 0, 0, 0);
    sA[nt] = z;
  }
  __builtin_amdgcn_s_setprio(0);
  if (MASK) {
    #pragma unroll
    for (int nt = 0; nt < 4; ++nt)
      #pragma unroll
      for (int r = 0; r < 4; ++r)
        if (nt * 16 + ll > wsub * 16 + lg * 4 + r) sA[nt][r] = -1e30f;
  }
  #pragma unroll
  for (int nt = 0; nt < 4; ++nt) {
    #pragma unroll
    for (int r = 0; r < 4; ++r) {
      float p = __builtin_amdgcn_exp2f(sA[nt][r]);
      psum[r] += p;
      int row = lg * 4 + r;
      int col = nt * 16 + ll;
      pw[row * 64 + (col ^ ((row & 7) << 3))] = f2bf(p);
    }
  }
  bf16x8 pf[2];
  {
    int sw = (ll & 7) << 3;
    pf[0] = *(const bf16x8*)&pw[ll * 64 + ((8 * lg) ^ sw)];
    pf[1] = *(const bf16x8*)&pw[ll * 64 + ((32 + 8 * lg) ^ sw)];
  }
  __builtin_amdgcn_s_setprio(1);
  #pragma unroll
  for (int nt2 = 0; nt2 < 4; ++nt2) {
    int vr = nt2 * 16 + ll;
    bf16x8 v0 = *(const bf16x8*)&Vbuf[vr * 64 + ((lg ^ (vr & 7)) << 3)];
    bf16x8 v1 = *(const bf16x8*)&Vbuf[vr * 64 + (((4 + lg) ^ (vr & 7)) << 3)];
    f32x4 a = accO[nt2];
    a = __builtin_amdgcn_mfma_f32_16x16x32_bf16(pf[0], v0, a, 0, 0, 0);
    a = __builtin_amdgcn_mfma_f32_16x16x32_bf16(pf[1], v1, a, 0, 0, 0);
    accO[nt2] = a;
  }
  __builtin_amdgcn_s_setprio(0);
}

__global__ __launch_bounds__(512, 4) void attn_router_kernel(
    const u16* __restrict__ qs, const u16* __restrict__ ks,
    const u16* __restrict__ vt, u16* __restrict__ osb,
    const u16* __restrict__ qb, const u16* __restrict__ wrut,
    const float* __restrict__ bru, const float* __restrict__ Wrd,
    const float* __restrict__ brd, float* __restrict__ rw) {
  __shared__ u16 smem[40960];        // 80 KB union
  const int tid = threadIdx.x;

  if (blockIdx.x >= 512) {
    // =================== ROUTER PATH (blocks 512..1023) ===================
    u16* As = smem;                  //  64x64
    u16* Bs = smem + 64 * 64;        // 256x64
    const int m0 = (blockIdx.x - 512) * 64;
    {                                // A tile: 512 granules, 1/thread
      int r = tid >> 3, g = tid & 7;
      bf16x8 x = *(const bf16x8*)&qb[(size_t)(m0 + r) * 64 + g * 8];
      *(bf16x8*)&As[r * 64 + ((g ^ (r & 7)) << 3)] = x;
    }
    #pragma unroll
    for (int i = 0; i < 4; ++i) {    // B tile: 2048 granules, 4/thread
      int gi = i * 512 + tid;
      int n = gi >> 3, g = gi & 7;
      bf16x8 x = *(const bf16x8*)&wrut[(size_t)n * 64 + g * 8];
      *(bf16x8*)&Bs[n * 64 + ((g ^ (n & 7)) << 3)] = x;
    }
    __syncthreads();
    if (tid < 256) {
      const int w = tid >> 6, l = tid & 63, lg = l >> 4, ll = l & 15;
      const int arow = w * 16 + ll;
      bf16x8 a0 = *(const bf16x8*)&As[arow * 64 + ((lg ^ (arow & 7)) << 3)];
      bf16x8 a1 = *(const bf16x8*)&As[arow * 64 + (((4 + lg) ^ (arow & 7)) << 3)];
      float p0a[4] = {0.f, 0.f, 0.f, 0.f};
      float p1a[4] = {0.f, 0.f, 0.f, 0.f};
      #pragma unroll
      for (int nt = 0; nt < 16; ++nt) {
        int n = nt * 16 + ll;
        bf16x8 b0 = *(const bf16x8*)&Bs[n * 64 + ((lg ^ (n & 7)) << 3)];
        bf16x8 b1 = *(const bf16x8*)&Bs[n * 64 + (((4 + lg) ^ (n & 7)) << 3)];
        f32x4 z = (f32x4){0.f, 0.f, 0.f, 0.f};
        z = __builtin_amdgcn_mfma_f32_16x16x32_bf16(a0, b0, z, 0, 0, 0);
        z = __builtin_amdgcn_mfma_f32_16x16x32_bf16(a1, b1, z, 0, 0, 0);
        float bu = bru[n];
        float w0 = Wrd[n * 2 + 0], w1 = Wrd[n * 2 + 1];
        #pragma unroll
        for (int r = 0; r < 4; ++r) {
          float h = z[r] + bu;
          float s = h / (1.f + __expf(-h));    // silu
          p0a[r] += s * w0;
          p1a[r] += s * w1;
        }
      }
      const float brd0 = brd[0], brd1 = brd[1];
      #pragma unroll
      for (int r = 0; r < 4; ++r) {
        float p0 = p0a[r], p1 = p1a[r];
        #pragma unroll
        for (int off = 8; off >= 1; off >>= 1) {
          p0 += __shfl_xor(p0, off, 16);
          p1 += __shfl_xor(p1, off, 16);
        }
        if (ll == 0) {
          float o0 = p0 + brd0, o1 = p1 + brd1;
          float mx = fmaxf(o0, o1);
          float e0 = __expf(o0 - mx), e1 = __expf(o1 - mx);
          float inv = 1.f / (e0 + e1);
          int row = m0 + w * 16 + lg * 4 + r;
          rw[(size_t)row * 2 + 0] = e0 * inv;
          rw[(size_t)row * 2 + 1] = e1 * inv;
        }
      }
    }
    return;
  }

  // ===================== ATTENTION PATH (blocks 0..511) =====================
  u16* Ks0 = smem;                   // Ks[2][128*64] = 32 KB
  u16* Vs0 = smem + 16384;           // Vs[2][2][64*64] = 32 KB
  u16* pb  = smem + 32768;           // pb[8][16*64] = 16 KB

  const int wgid = blockIdx.x;      // 0..511
  const int xcd = wgid & 7;
  const int local = wgid >> 3;      // 0..63
  int mm, px;
  if (local < 32) { mm = local >> 4; px = local & 15; }
  else { int s = local - 32; px = s >> 1; mm = 2 + (s & 1); }
  const int m = mm * 8 + xcd;       // matrix 0..31 = o*16+bh (XCD-local)
  const size_t mat = (size_t)m * L_ * D_;
  const u16* Q  = qs + mat;
  const u16* K  = ks + mat;
  const u16* VT = vt + mat;         // [d][key], stride L_
  u16* O = osb + mat;

  const int w  = tid >> 6;          // wave 0..7
  const int l  = tid & 63;
  const int lg = l >> 4;
  const int ll = l & 15;
  const int wsub = w & 3;
  const int qt = (w < 4) ? px : (31 - px);
  const int tq = qt >> 1;                    // diagonal 128-tile index
  const int T  = ((31 - px) >> 1) + 1;       // loop bound (covers long half)
  const int q0 = qt * 64 + wsub * 16;

  u16* pw = pb + w * (16 * 64);

  bf16x8 qf[2];
  {
    const u16* qp = Q + (size_t)(q0 + ll) * 64 + 8 * lg;
    qf[0] = *(const bf16x8*)(qp);
    qf[1] = *(const bf16x8*)(qp + 32);
  }

  f32x4 accO[4];
  #pragma unroll
  for (int i = 0; i < 4; ++i) accO[i] = (f32x4){0.f, 0.f, 0.f, 0.f};
  float psum[4] = {0.f, 0.f, 0.f, 0.f};

  // staging indices: K 1024 granules (2/thread), V 1024 granules (2/thread)
  const int krow = tid >> 3, kgr = tid & 7;                // K rows 0..63 (+64)
  const int koff = krow * 64 + ((kgr ^ (krow & 7)) << 3);  // +64*64 for second
  const int vrow = tid >> 4, vgr = tid & 15;               // V rows 0..31 (+32)
  const int vhalf = vgr >> 3, vg = vgr & 7;                // key-half, granule
  const int voff = vrow * 64 + ((vg ^ (vrow & 7)) << 3);   // +32*64 for second

  #define KS(buf) (Ks0 + (buf) * (128 * 64))
  #define VS(buf, half) (Vs0 + (buf) * (2 * 64 * 64) + (half) * (64 * 64))

  // ---- initial stage: tile 0 -> buffer 0 ----
  {
    const u16* kb = K;
    const u16* vb = VT;
    *(bf16x8*)&KS(0)[koff]            = *(const bf16x8*)&kb[krow * 64 + kgr * 8];
    *(bf16x8*)&KS(0)[koff + 64 * 64]  = *(const bf16x8*)&kb[(krow + 64) * 64 + kgr * 8];
    *(bf16x8*)&VS(0, vhalf)[voff]           = *(const bf16x8*)&vb[(size_t)vrow * L_ + vgr * 8];
    *(bf16x8*)&VS(0, vhalf)[voff + 32 * 64] = *(const bf16x8*)&vb[(size_t)(vrow + 32) * L_ + vgr * 8];
  }
  __syncthreads();

  int cur = 0;
  for (int t = 0; t < T; ++t) {
    const int tn = (t + 1 < T) ? t + 1 : t;
    // issue next tile's global loads (latency hides under compute)
    bf16x8 sk0, sk1, sv0, sv1;
    {
      const u16* kb = K + (size_t)(tn * 128) * 64;
      const u16* vb = VT + (size_t)(tn * 128);
      sk0 = *(const bf16x8*)&kb[krow * 64 + kgr * 8];
      sk1 = *(const bf16x8*)&kb[(krow + 64) * 64 + kgr * 8];
      sv0 = *(const bf16x8*)&vb[(size_t)vrow * L_ + vgr * 8];
      sv1 = *(const bf16x8*)&vb[(size_t)(vrow + 32) * L_ + vgr * 8];
    }
    // compute current 128-tile as two 64-key halves (wave-uniform branches)
    if (t < tq) {
      attn_tile<false>(KS(cur),           VS(cur, 0), pw, qf, accO, psum, lg, ll, wsub);
      attn_tile<false>(KS(cur) + 64 * 64, VS(cur, 1), pw, qf, accO, psum, lg, ll, wsub);
    } else if (t == tq) {
      if (qt & 1) {
        attn_tile<false>(KS(cur),           VS(cur, 0), pw, qf, accO, psum, lg, ll, wsub);
        attn_tile<true >(KS(cur) + 64 * 64, VS(cur, 1), pw, qf, accO, psum, lg, ll, wsub);
      } else {
        attn_tile<true >(KS(cur),           VS(cur, 0), pw, qf, accO, psum, lg, ll, wsub);
      }
    }
    // write staged regs -> other buffer
    *(bf16x8*)&KS(cur ^ 1)[koff]            = sk0;
    *(bf16x8*)&KS(cur ^ 1)[koff + 64 * 64]  = sk1;
    *(bf16x8*)&VS(cur ^ 1, vhalf)[voff]           = sv0;
    *(bf16x8*)&VS(cur ^ 1, vhalf)[voff + 32 * 64] = sv1;
    __syncthreads();
    cur ^= 1;
  }

  // ---- finalize: reduce psum across the 16 lanes of each row, write O ----
  #pragma unroll
  for (int r = 0; r < 4; ++r) {
    float ps = psum[r];
    #pragma unroll
    for (int off = 8; off >= 1; off >>= 1) ps += __shfl_xor(ps, off, 16);
    float inv = 1.f / ps;
    int qrow = q0 + lg * 4 + r;
    #pragma unroll
    for (int nt2 = 0; nt2 < 4; ++nt2)
      O[(size_t)qrow * 64 + nt2 * 16 + ll] = f2bf(accO[nt2][r] * inv);
  }
  #undef KS
  #undef VS
}

// ---------------------------------------------------------------------------
extern "C" void kernel_launch(void* const* d_in, const int* in_sizes, int n_in,
                              void* d_out, int out_size, void* d_ws, size_t ws_size,
                              hipStream_t stream) {
  const float* hs      = (const float*)d_in[0];
  const int*   pos_row = (const int*)d_in[1];
  const int*   pos_col = (const int*)d_in[2];
  const float* Wq = (const float*)d_in[3];  const float* bq = (const float*)d_in[4];
  const float* Wk = (const float*)d_in[5];  const float* bk = (const float*)d_in[6];
  const float* Wv = (const float*)d_in[7];  const float* bv = (const float*)d_in[8];
  const float* Wo = (const float*)d_in[9];  const float* bo = (const float*)d_in[10];
  const float* Wru = (const float*)d_in[11]; const float* bru = (const float*)d_in[12];
  const float* Wrd = (const float*)d_in[13]; const float* brd = (const float*)d_in[14];

  // Workspace layout. ~14M floats ~= 56 MB.
  float* ws = (float*)d_ws;
  float* cost = ws;                    // [2048][32]
  float* sint = cost + 65536;
  float* rw   = sint + 65536;          // (B*H*L, 2)
  u16*  osb   = (u16*)(rw + 65536);    // [2 ord](B,H,L,D) bf16 attn out (2*NQ u16)
  u16*  qs_b  = osb + 2 * NQ;          // [2 ord](B,H,L,D) bf16  (2*NQ u16)
  u16*  ks_b  = qs_b + 2 * NQ;         // (2*NQ u16)
  u16*  vt_b  = ks_b + 2 * NQ;         // [2 ord](B,H,D,L) bf16  (2*NQ u16)
  u16*  hs_b  = vt_b + 2 * NQ;         // (B,L,512) bf16         (NQ u16)
  u16*  ctx_b = hs_b + NQ;             // (unused; kept for layout stability)
  u16*  qb_b  = ctx_b + NQ;            // (B,H,L,D) bf16 q       (NQ u16)
  u16*  kb_b  = qb_b + NQ;             // (B,H,L,D) bf16 k       (NQ u16)
  u16*  vb_b  = kb_b + NQ;             // (B,H,L,D) bf16 v       (NQ u16)
  u16*  wt_b  = vb_b + NQ;             // [4][512][512] bf16
  u16*  wrut_b = wt_b + 4 * 512 * 512; // [256][64] bf16
  int*  sidx  = (int*)(wrut_b + 256 * 64);      // [B*2][L]
  int*  rank  = sidx + 4 * L_;                  // [B*2][L]

  prep_kernel<<<2593, 256, 0, stream>>>(hs, Wq, Wk, Wv, Wo, Wru, pos_row, pos_col,
                                        hs_b, wt_b, wrut_b, cost, sint, sidx, rank);
  gemm_bf16_kernel<1><<<dim3(32, 24), 256, 0, stream>>>(hs_b, wt_b, nullptr, nullptr,
                                                        nullptr, bq, bk, bv,
                                                        nullptr, qb_b, kb_b, vb_b);
  gather_kernel<<<9216, 256, 0, stream>>>(qb_b, kb_b, vb_b, pos_row, pos_col, sidx,
                                          cost, sint, qs_b, ks_b, vt_b);
  attn_router_kernel<<<1024, 512, 0, stream>>>(qs_b, ks_b, vt_b, osb,
                                               qb_b, wrut_b, bru, Wrd, brd, rw);
  gemm_bf16_kernel<0><<<dim3(32, 8), 256, 0, stream>>>(nullptr, wt_b, osb, rank, rw,
                                                       bo, nullptr, nullptr,
                                                       (float*)d_out, nullptr, nullptr, nullptr);
}

// Round 21
// 99.273 us; speedup vs baseline: 1.0967x; 1.0967x over previous
//
#include <hip/hip_runtime.h>
#include <hip/hip_bf16.h>
#include <math.h>

// Problem constants (B=2, L=2048, d_model=512, H=8, D=64, MAX_POS=2048)
#define B_ 2
#define L_ 2048
#define H_ 8
#define D_ 64
#define DM_ 512

typedef unsigned short u16;
typedef __attribute__((ext_vector_type(8))) short bf16x8;
typedef __attribute__((ext_vector_type(4))) float f32x4;

static const size_t NQ = (size_t)B_ * H_ * L_ * D_;   // 2,097,152 elems per (B,H,L,D) tensor

// Native fp32->bf16 (RNE) via the compiler's bfloat cast (round-20 validated:
// absmax bit-identical, fewer VALU ops than the manual 4-op RNE).
__device__ __forceinline__ u16 f2bf(float x) {
  __hip_bfloat16 h = __float2bfloat16(x);
  return *reinterpret_cast<u16*>(&h);
}
__device__ __forceinline__ float bf2f(u16 x) {
  union { unsigned u; float f; } v; v.u = ((unsigned)x) << 16; return v.f;
}

// ---------------------------------------------------------------------------
// Fused preprocessing (all independent; one launch):
//   blocks [0,2048)    : cast hs fp32 -> bf16
//   blocks [2048,2304) : transpose+cast W[4] -> wt bf16 [mat][n][k]
//   blocks [2304,2336) : stable rank (brute-force count of smaller keys)
//   blocks [2336,2592) : RoPE cos/sin table [2048][32]
//   block  2592        : transpose+cast Wru -> wrut bf16 [256][64]
// ---------------------------------------------------------------------------
__global__ __launch_bounds__(256) void prep_kernel(
    const float* __restrict__ hs,
    const float* __restrict__ Wq, const float* __restrict__ Wk,
    const float* __restrict__ Wv, const float* __restrict__ Wo,
    const float* __restrict__ Wru,
    const int* __restrict__ pos_row, const int* __restrict__ pos_col,
    u16* __restrict__ hsb, u16* __restrict__ wt, u16* __restrict__ wrut,
    float* __restrict__ cost, float* __restrict__ sint,
    int* __restrict__ sidx, int* __restrict__ rank) {
  __shared__ unsigned smbuf[2080];    // 8320 B: castWt tile (64x65 u16) / rank keys (2048 u32)
  const int blk = blockIdx.x;
  const int tid = threadIdx.x;

  if (blk < 2048) {                   // ---- cast_hs ----
    int g = blk * 256 + tid;
    float4 x = *(const float4*)&hs[(size_t)g * 4];
    ushort4 o;
    o.x = f2bf(x.x); o.y = f2bf(x.y); o.z = f2bf(x.z); o.w = f2bf(x.w);
    *(ushort4*)&hsb[(size_t)g * 4] = o;
  } else if (blk < 2304) {            // ---- castWt ----
    int idx = blk - 2048;             // 0..255
    u16 (*tile)[65] = (u16(*)[65])smbuf;
    const int mmat = idx >> 6;
    const float* W = (mmat == 0) ? Wq : (mmat == 1) ? Wk : (mmat == 2) ? Wv : Wo;
    const int n0 = (idx & 7) * 64, k0 = ((idx >> 3) & 7) * 64;
    {
      int r = tid >> 2, cq = tid & 3;
      const float* src = W + (size_t)(k0 + r) * 512 + n0 + cq * 16;
      #pragma unroll
      for (int j4 = 0; j4 < 4; ++j4) {
        float4 x = *(const float4*)&src[j4 * 4];
        int c = cq * 16 + j4 * 4;
        tile[r][c + 0] = f2bf(x.x); tile[r][c + 1] = f2bf(x.y);
        tile[r][c + 2] = f2bf(x.z); tile[r][c + 3] = f2bf(x.w);
      }
    }
    __syncthreads();
    {
      int n = tid >> 2, rq = tid & 3;
      u16 arr[16];
      #pragma unroll
      for (int i = 0; i < 16; ++i) arr[i] = tile[rq * 16 + i][n];
      u16* dst = wt + ((size_t)mmat * 512 + n0 + n) * 512 + k0 + rq * 16;
      *(uint4*)(dst)     = *(uint4*)&arr[0];
      *(uint4*)(dst + 8) = *(uint4*)&arr[8];
    }
  } else if (blk < 2336) {            // ---- rank ----
    unsigned* keys = smbuf;
    const int bx = blk - 2304;        // 0..31
    const int bo = bx >> 3, chunk = bx & 7;
    const int b = bo >> 1, o = bo & 1;
    const int* pos = (o ? pos_col : pos_row) + b * L_;
    for (int i = tid; i < L_; i += 256)
      keys[i] = (((unsigned)pos[i]) << 11) | (unsigned)i;
    __syncthreads();
    const int i = chunk * 256 + tid;
    const unsigned ki = keys[i];
    int cnt = 0;
    #pragma unroll 4
    for (int j = 0; j < L_; j += 4) {
      uint4 kj = *(const uint4*)&keys[j];
      cnt += (kj.x < ki) + (kj.y < ki) + (kj.z < ki) + (kj.w < ki);
    }
    sidx[bo * L_ + cnt] = i;
    rank[bo * L_ + i] = cnt;
  } else if (blk < 2592) {            // ---- rope_table ----
    int g = (blk - 2336) * 256 + tid; // 0..65535
    int f = g & 31, p = g >> 5;
    double th = pow(10000.0, -(double)(2 * f) / 64.0);
    float ang = (float)p * (float)th;
    cost[g] = cosf(ang);
    sint[g] = sinf(ang);
  } else {                            // ---- cast_wrut ----
    const int n = tid;
    #pragma unroll
    for (int k = 0; k < 64; ++k)
      wrut[n * 64 + k] = f2bf(Wru[k * 256 + n]);
  }
}

// ---------------------------------------------------------------------------
// bf16 MFMA GEMM: C(Mx512) = A(Mx512 bf16) @ Wt^T + bias, Wt is [n][k] bf16.
// Tile BM=128, BN=64, BK=64; 256 threads (4 waves).
// MODE 0: fp32 row-major out (final projection), bias b0, mat 3.
// MODE 1: fused QKV -> bf16 outputs Ob0/Ob1/Ob2 in (B,H,L,D) layout.
// ---------------------------------------------------------------------------
template <int MODE>
__global__ __launch_bounds__(256) void gemm_bf16_kernel(
    const u16* __restrict__ A, const u16* __restrict__ wt,
    const float* __restrict__ b0, const float* __restrict__ b1, const float* __restrict__ b2,
    float* __restrict__ Of,
    u16* __restrict__ Ob0, u16* __restrict__ Ob1, u16* __restrict__ Ob2) {
  const int m0 = blockIdx.x * 128;
  int by = blockIdx.y;
  int which = 0;
  if (MODE == 1) { which = by >> 3; by &= 7; }
  const int n0 = by * 64;
  const float* bias = (MODE == 0) ? b0 : (which == 0) ? b0 : (which == 1) ? b1 : b2;
  u16* Ob = (MODE == 0) ? nullptr : (which == 0) ? Ob0 : (which == 1) ? Ob1 : Ob2;
  const u16* Wt = wt + (size_t)((MODE == 0) ? 3 : which) * 512 * 512;

  __shared__ u16 As[128 * 64];
  __shared__ u16 Bs[64 * 64];

  const int tid = threadIdx.x;
  const int w  = tid >> 6;
  const int l  = tid & 63;
  const int lg = l >> 4;
  const int ll = l & 15;

  f32x4 acc[2][4];
  #pragma unroll
  for (int i = 0; i < 2; ++i)
    #pragma unroll
    for (int j = 0; j < 4; ++j) acc[i][j] = (f32x4){0.f, 0.f, 0.f, 0.f};

  for (int kb = 0; kb < 512; kb += 64) {
    #pragma unroll
    for (int i = 0; i < 4; ++i) {           // A tile: 1024 granules
      int gi = i * 256 + tid;
      int r = gi >> 3, g = gi & 7;
      bf16x8 x = *(const bf16x8*)&A[(size_t)(m0 + r) * 512 + kb + g * 8];
      *(bf16x8*)&As[r * 64 + ((g ^ (r & 7)) << 3)] = x;
    }
    #pragma unroll
    for (int i = 0; i < 2; ++i) {           // B tile: 512 granules
      int gi = i * 256 + tid;
      int n = gi >> 3, g = gi & 7;
      bf16x8 x = *(const bf16x8*)&Wt[(size_t)(n0 + n) * 512 + kb + g * 8];
      *(bf16x8*)&Bs[n * 64 + ((g ^ (n & 7)) << 3)] = x;
    }
    __syncthreads();
    #pragma unroll
    for (int kc = 0; kc < 2; ++kc) {
      bf16x8 ar[2], br[4];
      #pragma unroll
      for (int mr = 0; mr < 2; ++mr) {
        int row = w * 32 + mr * 16 + ll;
        ar[mr] = *(const bf16x8*)&As[row * 64 + (((kc * 4 + lg) ^ (row & 7)) << 3)];
      }
      #pragma unroll
      for (int nt = 0; nt < 4; ++nt) {
        int n = nt * 16 + ll;
        br[nt] = *(const bf16x8*)&Bs[n * 64 + (((kc * 4 + lg) ^ (n & 7)) << 3)];
      }
      #pragma unroll
      for (int mr = 0; mr < 2; ++mr)
        #pragma unroll
        for (int nt = 0; nt < 4; ++nt)
          acc[mr][nt] = __builtin_amdgcn_mfma_f32_16x16x32_bf16(ar[mr], br[nt], acc[mr][nt], 0, 0, 0);
    }
    __syncthreads();
  }

  #pragma unroll
  for (int mr = 0; mr < 2; ++mr) {
    #pragma unroll
    for (int nt = 0; nt < 4; ++nt) {
      int col = n0 + nt * 16 + ll;
      float bv = bias[col];
      #pragma unroll
      for (int r = 0; r < 4; ++r) {
        int row = m0 + w * 32 + mr * 16 + lg * 4 + r;
        float val = acc[mr][nt][r] + bv;
        if (MODE == 0) {
          Of[(size_t)row * 512 + col] = val;
        } else {
          int b = row >> 11, ls = row & 2047;
          int h = col >> 6, d = col & 63;
          size_t idx = (((size_t)(b * 8 + h)) * L_ + ls) * D_ + d;
          Ob[idx] = f2bf(val);
        }
      }
    }
  }
}

// ---------------------------------------------------------------------------
// Fused gather (bf16 inputs from the QKV GEMM):
//   blocks [0,8192)    : RoPE + gather q,k -> sorted bf16.
//     Q pre-scale folds log2(e): 0.125*log2(e) — attention computes softmax
//     in the exp2 domain (p = exp2(s) = exp(s_orig/8), one v_exp per score).
//   blocks [8192,9216) : gather + transpose V -> vt [o][bh][d][key]
// ---------------------------------------------------------------------------
#define QSCALE 0.18033688011f   // 0.125 * log2(e)

__global__ __launch_bounds__(256) void gather_kernel(
    const u16* __restrict__ qb, const u16* __restrict__ kb, const u16* __restrict__ vb,
    const int* __restrict__ pos_row, const int* __restrict__ pos_col,
    const int* __restrict__ sidx,
    const float* __restrict__ cost, const float* __restrict__ sint,
    u16* __restrict__ qs, u16* __restrict__ ks, u16* __restrict__ vt) {
  __shared__ u16 tile[64][72];        // stride 72 u16 = 144 B (16B-aligned rows)
  const int blk = blockIdx.x;
  const int tid = threadIdx.x;

  if (blk < 8192) {                   // ---- rope_gather ----
    int g = blk * 256 + tid;          // 2,097,152 total
    int i5 = g & 31;
    int r  = (g >> 5) & 2047;
    int h  = (g >> 16) & 7;
    int b  = (g >> 19) & 1;
    int o  = (g >> 20) & 1;

    int bo = b * 2 + o;
    int lsrc = sidx[bo * L_ + r];
    const int* pos = o ? pos_col : pos_row;
    int p = pos[b * L_ + lsrc];

    size_t srcoff = (((size_t)(b * 8 + h)) * L_ + lsrc) * D_ + i5 * 2;
    unsigned qu = *(const unsigned*)&qb[srcoff];
    unsigned ku = *(const unsigned*)&kb[srcoff];
    float q2x = bf2f((u16)qu), q2y = bf2f((u16)(qu >> 16));
    float k2x = bf2f((u16)ku), k2y = bf2f((u16)(ku >> 16));

    int f0 = (2 * i5) & 31;
    int f1 = (2 * i5 + 1) & 31;
    float c0 = cost[p * 32 + f0], c1 = cost[p * 32 + f1];
    float s0 = sint[p * 32 + f0], s1 = sint[p * 32 + f1];

    float qx = (q2x * c0 - q2y * s0) * QSCALE;
    float qy = (q2y * c1 + q2x * s1) * QSCALE;
    float kx = k2x * c0 - k2y * s0;
    float ky = k2y * c1 + k2x * s1;

    size_t dst = (((size_t)(o * 16 + b * 8 + h)) * L_ + r) * D_ + i5 * 2;
    qs[dst] = f2bf(qx); qs[dst + 1] = f2bf(qy);
    ks[dst] = f2bf(kx); ks[dst + 1] = f2bf(ky);
  } else {                            // ---- vt (pure gather+transpose copy) ----
    int idx = blk - 8192;             // 0..1023
    const int rt = idx & 31, bh = (idx >> 5) & 15, o = idx >> 9;
    const int b = bh >> 3;
    {
      int r = tid >> 2, dq = tid & 3;
      int lsrc = sidx[(b * 2 + o) * L_ + rt * 64 + r];
      const u16* src = vb + ((size_t)bh * L_ + lsrc) * D_ + dq * 16;
      *(uint4*)&tile[r][dq * 16]     = *(const uint4*)&src[0];
      *(uint4*)&tile[r][dq * 16 + 8] = *(const uint4*)&src[8];
    }
    __syncthreads();
    {
      int d = tid >> 2, rq = tid & 3;
      u16 arr[16];
      #pragma unroll
      for (int i = 0; i < 16; ++i) arr[i] = tile[rq * 16 + i][d];
      u16* dst = vt + (((size_t)(o * 16 + bh)) * D_ + d) * L_ + rt * 64 + rq * 16;
      *(uint4*)(dst)     = *(uint4*)&arr[0];
      *(uint4*)(dst + 8) = *(uint4*)&arr[8];
    }
  }
}

// ---------------------------------------------------------------------------
// Merged attention + router launch (1024 blocks x 512 threads):
//   blocks [0,512)    : causal flash attention
//   blocks [512,1024) : fused MFMA router (independent — fills attn drain)
// ---------------------------------------------------------------------------
template <bool MASK>
__device__ __forceinline__ void attn_tile(
    const u16* __restrict__ Kbuf,    // rows=keys(64), stride 64, swizzled
    const u16* __restrict__ Vbuf,    // rows=d(64), stride 64 (one key-half)
    u16* __restrict__ pw,
    const bf16x8 qf[2], f32x4 accO[4], float psum[4],
    int lg, int ll, int wsub) {
  f32x4 sA[4];
  __builtin_amdgcn_s_setprio(1);
  #pragma unroll
  for (int nt = 0; nt < 4; ++nt) {
    int kr = nt * 16 + ll;
    bf16x8 k0 = *(const bf16x8*)&Kbuf[kr * 64 + ((lg ^ (kr & 7)) << 3)];
    bf16x8 k1 = *(const bf16x8*)&Kbuf[kr * 64 + (((4 + lg) ^ (kr & 7)) << 3)];
    f32x4 z = (f32x4){0.f, 0.f, 0.f, 0.f};
    z = __builtin_amdgcn_mfma_f32_16x16x32_bf16(qf[0], k0, z, 0, 0, 0);
    z = __builtin_amdgcn_mfma_f32_16x16x32_bf16(qf[1], k1, z, 0, 0, 0);
    sA[nt] = z;
  }
  __builtin_amdgcn_s_setprio(0);
  if (MASK) {
    #pragma unroll
    for (int nt = 0; nt < 4; ++nt)
      #pragma unroll
      for (int r = 0; r < 4; ++r)
        if (nt * 16 + ll > wsub * 16 + lg * 4 + r) sA[nt][r] = -1e30f;
  }
  #pragma unroll
  for (int nt = 0; nt < 4; ++nt) {
    #pragma unroll
    for (int r = 0; r < 4; ++r) {
      float p = __builtin_amdgcn_exp2f(sA[nt][r]);
      psum[r] += p;
      int row = lg * 4 + r;
      int col = nt * 16 + ll;
      pw[row * 64 + (col ^ ((row & 7) << 3))] = f2bf(p);
    }
  }
  bf16x8 pf[2];
  {
    int sw = (ll & 7) << 3;
    pf[0] = *(const bf16x8*)&pw[ll * 64 + ((8 * lg) ^ sw)];
    pf[1] = *(const bf16x8*)&pw[ll * 64 + ((32 + 8 * lg) ^ sw)];
  }
  __builtin_amdgcn_s_setprio(1);
  #pragma unroll
  for (int nt2 = 0; nt2 < 4; ++nt2) {
    int vr = nt2 * 16 + ll;
    bf16x8 v0 = *(const bf16x8*)&Vbuf[vr * 64 + ((lg ^ (vr & 7)) << 3)];
    bf16x8 v1 = *(const bf16x8*)&Vbuf[vr * 64 + (((4 + lg) ^ (vr & 7)) << 3)];
    f32x4 a = accO[nt2];
    a = __builtin_amdgcn_mfma_f32_16x16x32_bf16(pf[0], v0, a, 0, 0, 0);
    a = __builtin_amdgcn_mfma_f32_16x16x32_bf16(pf[1], v1, a, 0, 0, 0);
    accO[nt2] = a;
  }
  __builtin_amdgcn_s_setprio(0);
}

__global__ __launch_bounds__(512, 4) void attn_router_kernel(
    const u16* __restrict__ qs, const u16* __restrict__ ks,
    const u16* __restrict__ vt, u16* __restrict__ osb,
    const u16* __restrict__ qb, const u16* __restrict__ wrut,
    const float* __restrict__ bru, const float* __restrict__ Wrd,
    const float* __restrict__ brd, float* __restrict__ rw) {
  __shared__ u16 smem[40960];        // 80 KB union
  const int tid = threadIdx.x;

  if (blockIdx.x >= 512) {
    // =================== ROUTER PATH (blocks 512..1023) ===================
    u16* As = smem;                  //  64x64
    u16* Bs = smem + 64 * 64;        // 256x64
    const int m0 = (blockIdx.x - 512) * 64;
    {                                // A tile: 512 granules, 1/thread
      int r = tid >> 3, g = tid & 7;
      bf16x8 x = *(const bf16x8*)&qb[(size_t)(m0 + r) * 64 + g * 8];
      *(bf16x8*)&As[r * 64 + ((g ^ (r & 7)) << 3)] = x;
    }
    #pragma unroll
    for (int i = 0; i < 4; ++i) {    // B tile: 2048 granules, 4/thread
      int gi = i * 512 + tid;
      int n = gi >> 3, g = gi & 7;
      bf16x8 x = *(const bf16x8*)&wrut[(size_t)n * 64 + g * 8];
      *(bf16x8*)&Bs[n * 64 + ((g ^ (n & 7)) << 3)] = x;
    }
    __syncthreads();
    if (tid < 256) {
      const int w = tid >> 6, l = tid & 63, lg = l >> 4, ll = l & 15;
      const int arow = w * 16 + ll;
      bf16x8 a0 = *(const bf16x8*)&As[arow * 64 + ((lg ^ (arow & 7)) << 3)];
      bf16x8 a1 = *(const bf16x8*)&As[arow * 64 + (((4 + lg) ^ (arow & 7)) << 3)];
      float p0a[4] = {0.f, 0.f, 0.f, 0.f};
      float p1a[4] = {0.f, 0.f, 0.f, 0.f};
      #pragma unroll
      for (int nt = 0; nt < 16; ++nt) {
        int n = nt * 16 + ll;
        bf16x8 b0 = *(const bf16x8*)&Bs[n * 64 + ((lg ^ (n & 7)) << 3)];
        bf16x8 b1 = *(const bf16x8*)&Bs[n * 64 + (((4 + lg) ^ (n & 7)) << 3)];
        f32x4 z = (f32x4){0.f, 0.f, 0.f, 0.f};
        z = __builtin_amdgcn_mfma_f32_16x16x32_bf16(a0, b0, z, 0, 0, 0);
        z = __builtin_amdgcn_mfma_f32_16x16x32_bf16(a1, b1, z, 0, 0, 0);
        float bu = bru[n];
        float w0 = Wrd[n * 2 + 0], w1 = Wrd[n * 2 + 1];
        #pragma unroll
        for (int r = 0; r < 4; ++r) {
          float h = z[r] + bu;
          float s = h / (1.f + __expf(-h));    // silu
          p0a[r] += s * w0;
          p1a[r] += s * w1;
        }
      }
      const float brd0 = brd[0], brd1 = brd[1];
      #pragma unroll
      for (int r = 0; r < 4; ++r) {
        float p0 = p0a[r], p1 = p1a[r];
        #pragma unroll
        for (int off = 8; off >= 1; off >>= 1) {
          p0 += __shfl_xor(p0, off, 16);
          p1 += __shfl_xor(p1, off, 16);
        }
        if (ll == 0) {
          float o0 = p0 + brd0, o1 = p1 + brd1;
          float mx = fmaxf(o0, o1);
          float e0 = __expf(o0 - mx), e1 = __expf(o1 - mx);
          float inv = 1.f / (e0 + e1);
          int row = m0 + w * 16 + lg * 4 + r;
          rw[(size_t)row * 2 + 0] = e0 * inv;
          rw[(size_t)row * 2 + 1] = e1 * inv;
        }
      }
    }
    return;
  }

  // ===================== ATTENTION PATH (blocks 0..511) =====================
  u16* Ks0 = smem;                   // Ks[2][128*64] = 32 KB
  u16* Vs0 = smem + 16384;           // Vs[2][2][64*64] = 32 KB
  u16* pb  = smem + 32768;           // pb[8][16*64] = 16 KB

  const int wgid = blockIdx.x;      // 0..511
  const int xcd = wgid & 7;
  const int local = wgid >> 3;      // 0..63
  int mm, px;
  if (local < 32) { mm = local >> 4; px = local & 15; }
  else { int s = local - 32; px = s >> 1; mm = 2 + (s & 1); }
  const int m = mm * 8 + xcd;       // matrix 0..31 = o*16+bh (XCD-local)
  const size_t mat = (size_t)m * L_ * D_;
  const u16* Q  = qs + mat;
  const u16* K  = ks + mat;
  const u16* VT = vt + mat;         // [d][key], stride L_
  u16* O = osb + mat;

  const int w  = tid >> 6;          // wave 0..7
  const int l  = tid & 63;
  const int lg = l >> 4;
  const int ll = l & 15;
  const int wsub = w & 3;
  const int qt = (w < 4) ? px : (31 - px);
  const int tq = qt >> 1;                    // diagonal 128-tile index
  const int T  = ((31 - px) >> 1) + 1;       // loop bound (covers long half)
  const int q0 = qt * 64 + wsub * 16;

  u16* pw = pb + w * (16 * 64);

  bf16x8 qf[2];
  {
    const u16* qp = Q + (size_t)(q0 + ll) * 64 + 8 * lg;
    qf[0] = *(const bf16x8*)(qp);
    qf[1] = *(const bf16x8*)(qp + 32);
  }

  f32x4 accO[4];
  #pragma unroll
  for (int i = 0; i < 4; ++i) accO[i] = (f32x4){0.f, 0.f, 0.f, 0.f};
  float psum[4] = {0.f, 0.f, 0.f, 0.f};

  // staging indices: K 1024 granules (2/thread), V 1024 granules (2/thread)
  const int krow = tid >> 3, kgr = tid & 7;                // K rows 0..63 (+64)
  const int koff = krow * 64 + ((kgr ^ (krow & 7)) << 3);  // +64*64 for second
  const int vrow = tid >> 4, vgr = tid & 15;               // V rows 0..31 (+32)
  const int vhalf = vgr >> 3, vg = vgr & 7;                // key-half, granule
  const int voff = vrow * 64 + ((vg ^ (vrow & 7)) << 3);   // +32*64 for second

  #define KS(buf) (Ks0 + (buf) * (128 * 64))
  #define VS(buf, half) (Vs0 + (buf) * (2 * 64 * 64) + (half) * (64 * 64))

  // ---- initial stage: tile 0 -> buffer 0 ----
  {
    const u16* kb = K;
    const u16* vb = VT;
    *(bf16x8*)&KS(0)[koff]            = *(const bf16x8*)&kb[krow * 64 + kgr * 8];
    *(bf16x8*)&KS(0)[koff + 64 * 64]  = *(const bf16x8*)&kb[(krow + 64) * 64 + kgr * 8];
    *(bf16x8*)&VS(0, vhalf)[voff]           = *(const bf16x8*)&vb[(size_t)vrow * L_ + vgr * 8];
    *(bf16x8*)&VS(0, vhalf)[voff + 32 * 64] = *(const bf16x8*)&vb[(size_t)(vrow + 32) * L_ + vgr * 8];
  }
  __syncthreads();

  int cur = 0;
  for (int t = 0; t < T; ++t) {
    const int tn = (t + 1 < T) ? t + 1 : t;
    // issue next tile's global loads (latency hides under compute)
    bf16x8 sk0, sk1, sv0, sv1;
    {
      const u16* kb = K + (size_t)(tn * 128) * 64;
      const u16* vb = VT + (size_t)(tn * 128);
      sk0 = *(const bf16x8*)&kb[krow * 64 + kgr * 8];
      sk1 = *(const bf16x8*)&kb[(krow + 64) * 64 + kgr * 8];
      sv0 = *(const bf16x8*)&vb[(size_t)vrow * L_ + vgr * 8];
      sv1 = *(const bf16x8*)&vb[(size_t)(vrow + 32) * L_ + vgr * 8];
    }
    // compute current 128-tile as two 64-key halves (wave-uniform branches)
    if (t < tq) {
      attn_tile<false>(KS(cur),           VS(cur, 0), pw, qf, accO, psum, lg, ll, wsub);
      attn_tile<false>(KS(cur) + 64 * 64, VS(cur, 1), pw, qf, accO, psum, lg, ll, wsub);
    } else if (t == tq) {
      if (qt & 1) {
        attn_tile<false>(KS(cur),           VS(cur, 0), pw, qf, accO, psum, lg, ll, wsub);
        attn_tile<true >(KS(cur) + 64 * 64, VS(cur, 1), pw, qf, accO, psum, lg, ll, wsub);
      } else {
        attn_tile<true >(KS(cur),           VS(cur, 0), pw, qf, accO, psum, lg, ll, wsub);
      }
    }
    // write staged regs -> other buffer
    *(bf16x8*)&KS(cur ^ 1)[koff]            = sk0;
    *(bf16x8*)&KS(cur ^ 1)[koff + 64 * 64]  = sk1;
    *(bf16x8*)&VS(cur ^ 1, vhalf)[voff]           = sv0;
    *(bf16x8*)&VS(cur ^ 1, vhalf)[voff + 32 * 64] = sv1;
    __syncthreads();
    cur ^= 1;
  }

  // ---- finalize: reduce psum across the 16 lanes of each row, write O ----
  #pragma unroll
  for (int r = 0; r < 4; ++r) {
    float ps = psum[r];
    #pragma unroll
    for (int off = 8; off >= 1; off >>= 1) ps += __shfl_xor(ps, off, 16);
    float inv = 1.f / ps;
    int qrow = q0 + lg * 4 + r;
    #pragma unroll
    for (int nt2 = 0; nt2 < 4; ++nt2)
      O[(size_t)qrow * 64 + nt2 * 16 + ll] = f2bf(accO[nt2][r] * inv);
  }
  #undef KS
  #undef VS
}

// ---------------------------------------------------------------------------
// Combine -> bf16 ctx: ctx_b[b][l][h*64+d] = w0*os_row[...] + w1*os_col[...]
// 512 blocks x 8 rows each.
// ---------------------------------------------------------------------------
__global__ __launch_bounds__(256) void combine_kernel(
    const u16* __restrict__ osb, const int* __restrict__ rank,
    const float* __restrict__ rw, u16* __restrict__ ctxb) {
  const int t = threadIdx.x;
  #pragma unroll
  for (int it = 0; it < 8; ++it) {
    const int bl = blockIdx.x * 8 + it;   // 0..4095
    const int b = bl >> 11, l = bl & 2047;
    const int rr = rank[(b * 2 + 0) * L_ + l];
    const int rc = rank[(b * 2 + 1) * L_ + l];
    int col = 2 * t;
    int h = col >> 6, d = col & 63;
    int bh = b * 8 + h;
    float w0 = rw[(((size_t)bh) * L_ + l) * 2 + 0];
    float w1 = rw[(((size_t)bh) * L_ + l) * 2 + 1];
    ushort2 vr = *(const ushort2*)&osb[(((size_t)(0 * 16 + bh)) * L_ + rr) * D_ + d];
    ushort2 vc = *(const ushort2*)&osb[(((size_t)(1 * 16 + bh)) * L_ + rc) * D_ + d];
    ushort2 out;
    out.x = f2bf(w0 * bf2f(vr.x) + w1 * bf2f(vc.x));
    out.y = f2bf(w0 * bf2f(vr.y) + w1 * bf2f(vc.y));
    *(ushort2*)&ctxb[(size_t)bl * 512 + col] = out;
  }
}

// ---------------------------------------------------------------------------
extern "C" void kernel_launch(void* const* d_in, const int* in_sizes, int n_in,
                              void* d_out, int out_size, void* d_ws, size_t ws_size,
                              hipStream_t stream) {
  const float* hs      = (const float*)d_in[0];
  const int*   pos_row = (const int*)d_in[1];
  const int*   pos_col = (const int*)d_in[2];
  const float* Wq = (const float*)d_in[3];  const float* bq = (const float*)d_in[4];
  const float* Wk = (const float*)d_in[5];  const float* bk = (const float*)d_in[6];
  const float* Wv = (const float*)d_in[7];  const float* bv = (const float*)d_in[8];
  const float* Wo = (const float*)d_in[9];  const float* bo = (const float*)d_in[10];
  const float* Wru = (const float*)d_in[11]; const float* bru = (const float*)d_in[12];
  const float* Wrd = (const float*)d_in[13]; const float* brd = (const float*)d_in[14];

  // Workspace layout. ~14M floats ~= 56 MB.
  float* ws = (float*)d_ws;
  float* cost = ws;                    // [2048][32]
  float* sint = cost + 65536;
  float* rw   = sint + 65536;          // (B*H*L, 2)
  u16*  osb   = (u16*)(rw + 65536);    // [2 ord](B,H,L,D) bf16 attn out (2*NQ u16)
  u16*  qs_b  = osb + 2 * NQ;          // [2 ord](B,H,L,D) bf16  (2*NQ u16)
  u16*  ks_b  = qs_b + 2 * NQ;         // (2*NQ u16)
  u16*  vt_b  = ks_b + 2 * NQ;         // [2 ord](B,H,D,L) bf16  (2*NQ u16)
  u16*  hs_b  = vt_b + 2 * NQ;         // (B,L,512) bf16         (NQ u16)
  u16*  ctx_b = hs_b + NQ;             // (B,L,512) bf16         (NQ u16)
  u16*  qb_b  = ctx_b + NQ;            // (B,H,L,D) bf16 q       (NQ u16)
  u16*  kb_b  = qb_b + NQ;             // (B,H,L,D) bf16 k       (NQ u16)
  u16*  vb_b  = kb_b + NQ;             // (B,H,L,D) bf16 v       (NQ u16)
  u16*  wt_b  = vb_b + NQ;             // [4][512][512] bf16
  u16*  wrut_b = wt_b + 4 * 512 * 512; // [256][64] bf16
  int*  sidx  = (int*)(wrut_b + 256 * 64);      // [B*2][L]
  int*  rank  = sidx + 4 * L_;                  // [B*2][L]

  prep_kernel<<<2593, 256, 0, stream>>>(hs, Wq, Wk, Wv, Wo, Wru, pos_row, pos_col,
                                        hs_b, wt_b, wrut_b, cost, sint, sidx, rank);
  gemm_bf16_kernel<1><<<dim3(32, 24), 256, 0, stream>>>(hs_b, wt_b, bq, bk, bv,
                                                        nullptr, qb_b, kb_b, vb_b);
  gather_kernel<<<9216, 256, 0, stream>>>(qb_b, kb_b, vb_b, pos_row, pos_col, sidx,
                                          cost, sint, qs_b, ks_b, vt_b);
  attn_router_kernel<<<1024, 512, 0, stream>>>(qs_b, ks_b, vt_b, osb,
                                               qb_b, wrut_b, bru, Wrd, brd, rw);
  combine_kernel<<<512, 256, 0, stream>>>(osb, rank, rw, ctx_b);
  gemm_bf16_kernel<0><<<dim3(32, 8), 256, 0, stream>>>(ctx_b, wt_b, bo, nullptr, nullptr,
                                                       (float*)d_out, nullptr, nullptr, nullptr);
}